// Round 2
// baseline (235.386 us; speedup 1.0000x reference)
//
#include <hip/hip_runtime.h>

// NewtonImplicitNet via Picard iteration, MFMA, 16-round edition.
// R18: critical-path VALU diet (bit-identical math; absmax must stay
// 0.005859375 exactly).
//  (1) x hi/lo f16 split moved from the 25-stage GEMM loop (~24 VALU/stage
//      on the critical path) into the LDS staging pass (parallel, one-touch).
//      GEMM inner loop now reads f16x8 fragments straight from LDS; 25
//      uniform stages (pad zeros staged as zeros).
//  (2) Picard-round write split across dup quads: quads 2,3 hold bit-exact
//      duplicates of quads 0,1's D rows, so each quad now writes 2 rows ->
//      per-lane tanh chain in each round write drops 4 -> 2.
// Predicted -1.5..3 us. If <1 us, GEMM phase is latency-bound -> pivot.

#define B_ROWS  2048
#define D_IN    784
#define UNITS   128
#define D_OUT   10
#define RPB     8       // rows per block -> 256 blocks, rows 0..7 real in M=16
#define THREADS 512
#define NIT     4       // even (buffer parity: final read = buf 1, z0 -> buf 0)
#define ZSTR    138     // f16 Z row stride: 69 dwords = 5 mod 32 (2-way max)
#define XF16S   808     // f16 x row stride: 404 dwords = 20 mod 32 (spread)
#define KPAD    800     // zero-padded K for input GEMM: 25 stages x 32

// f16 workspace layout (element offsets)
#define OFF_WIN  0                              // 128 x KPAD
#define OFF_WB   (UNITS * KPAD)                 // 102400: then 4 x 128 x 128
#define OFF_WOUT (OFF_WB + 4 * UNITS * UNITS)   // 167936: 10 x 128
#define WS_ELEMS (OFF_WOUT + D_OUT * UNITS)     // 169216 f16 = 338 KB << ws

typedef _Float16 f16x8 __attribute__((ext_vector_type(8)));
typedef float    f32x4 __attribute__((ext_vector_type(4)));

__device__ __forceinline__ float rcp_fast(float x) { return __builtin_amdgcn_rcpf(x); }

__device__ __forceinline__ float tanh_fast(float x) {
  float e = __expf(2.0f * x);
  return 1.0f - 2.0f * rcp_fast(e + 1.0f);
}

__device__ __forceinline__ f16x8 cvt8(f32x4 a, f32x4 b) {
  f16x8 r;
  r[0] = (_Float16)a[0]; r[1] = (_Float16)a[1]; r[2] = (_Float16)a[2]; r[3] = (_Float16)a[3];
  r[4] = (_Float16)b[0]; r[5] = (_Float16)b[1]; r[6] = (_Float16)b[2]; r[7] = (_Float16)b[3];
  return r;
}
__device__ __forceinline__ f16x8 res8(f32x4 a, f32x4 b, f16x8 hi) {
  f16x8 r;
  r[0] = (_Float16)(a[0] - (float)hi[0]); r[1] = (_Float16)(a[1] - (float)hi[1]);
  r[2] = (_Float16)(a[2] - (float)hi[2]); r[3] = (_Float16)(a[3] - (float)hi[3]);
  r[4] = (_Float16)(b[0] - (float)hi[4]); r[5] = (_Float16)(b[1] - (float)hi[5]);
  r[6] = (_Float16)(b[2] - (float)hi[6]); r[7] = (_Float16)(b[3] - (float)hi[7]);
  return r;
}

#define MFMA(a, b, c) __builtin_amdgcn_mfma_f32_16x16x32_f16((a), (b), (c), 0, 0, 0)

// Fragment conventions (validated R4-R15):
//   A: lane holds A[m=lo16][k = 32s + quad*8 + j], j=0..7
//   B: lane holds B[k = 32s + quad*8 + j][n=lo16]  (= Wrow[n][k..] row-major)
//   C/D: lane holds D[m = quad*4 + i][n=lo16], i=0..3
// D rows depend only on A rows -> A rows 8..15 dup rows 0..7 BIT-EXACTLY
// (same A content, same B) -> quads 2,3 hold duplicate D rows, exploited
// by the split writes below.

// ---- prep: round all weights to f16 once (bit-identical to in-kernel cvt8) ----
__global__ void prep_weights(const float* __restrict__ W_in,
                             const float* __restrict__ W1,
                             const float* __restrict__ W2,
                             const float* __restrict__ W3,
                             const float* __restrict__ W4,
                             const float* __restrict__ W_out,
                             _Float16* __restrict__ wsh)
{
  const int i = blockIdx.x * blockDim.x + threadIdx.x;
  if (i < OFF_WB) {                       // W_in, zero-padded K 784 -> 800
    const int u = i / KPAD;
    const int k = i - u * KPAD;
    wsh[i] = (k < D_IN) ? (_Float16)W_in[u * D_IN + k] : (_Float16)0.f;
  } else if (i < OFF_WOUT) {              // W1..W4 row-major 128x128
    const int j = i - OFF_WB;
    const int w = j >> 14;
    const int rc = j & 16383;
    const float* Wp = (w == 0) ? W1 : (w == 1) ? W2 : (w == 2) ? W3 : W4;
    wsh[i] = (_Float16)Wp[rc];
  } else if (i < WS_ELEMS) {              // W_out 10x128
    wsh[i] = (_Float16)W_out[i - OFF_WOUT];
  }
}

__global__ __launch_bounds__(THREADS, 1) void fused_net(
    const float* __restrict__ x,
    const float* __restrict__ b_in,
    const float* __restrict__ b_out,
    const _Float16* __restrict__ wsh,
    float* __restrict__ out)
{
  __shared__ __align__(16) _Float16 Zb[2][RPB][ZSTR];   // ~4.4 KB
  __shared__ __align__(16) _Float16 XsH[RPB][XF16S];    // ~12.9 KB x-hi
  __shared__ __align__(16) _Float16 XsL[RPB][XF16S];    // ~12.9 KB x-lo

  const int t    = threadIdx.x;
  const int wave = t >> 6;        // 0..7, N-tile: units [16w, 16w+16)
  const int l    = t & 63;
  const int lo16 = l & 15;
  const int quad = l >> 4;
  const int u0   = wave * 16;
  const int r0   = blockIdx.x * RPB;

  const float bi = b_in[u0 + lo16];   // early scalar load

  // ---- W1 fragments for wb=0: straight f16 loads (issued early, pending) ----
  f16x8 wf[4];
  {
    const _Float16* a = wsh + OFF_WB + (size_t)(u0 + lo16) * UNITS;
#pragma unroll
    for (int s = 0; s < 4; ++s)
      wf[s] = *(const f16x8*)(a + s * 32 + quad * 8);
  }

  // ---- head fragments hoisted: wave 0 loads W_out/b_out NOW (regs) ----
  f16x8 bf0 = {}, bf1 = {}, bf2 = {}, bf3 = {};
  float bo = 0.f;
  if (wave == 0) {
    const int cls = (lo16 < D_OUT) ? lo16 : 0;
    const _Float16* wo = wsh + OFF_WOUT + (size_t)cls * UNITS;
    if (lo16 < D_OUT) {
      bf0 = *(const f16x8*)(wo + 0 * 32 + quad * 8);
      bf1 = *(const f16x8*)(wo + 1 * 32 + quad * 8);
      bf2 = *(const f16x8*)(wo + 2 * 32 + quad * 8);
      bf3 = *(const f16x8*)(wo + 3 * 32 + quad * 8);
      bo  = b_out[cls];
    }
  }

  // ---- W_in fragment ring: first 4 stages issued before x staging ----
  const _Float16* wr = wsh + OFF_WIN + (size_t)(u0 + lo16) * KPAD;
  f16x8 WB[4];
#pragma unroll
  for (int j = 0; j < 4; ++j)
    WB[j] = *(const f16x8*)(wr + j * 32 + quad * 8);

  // ---- stage x rows into LDS as f16 hi/lo (one-touch split; zero-padded) ----
  for (int i = t; i < RPB * (KPAD / 8); i += THREADS) {   // 800 8-elem slots
    const int r = i / (KPAD / 8);
    const int c = i - r * (KPAD / 8);
    f32x4 a = {0.f, 0.f, 0.f, 0.f}, b = {0.f, 0.f, 0.f, 0.f};
    if (c < D_IN / 8) {   // c*8+8 <= 784 for c < 98; 98,99 stay zero
      const float* p = x + (size_t)(r0 + r) * D_IN + c * 8;
      a = *(const f32x4*)p;
      b = *(const f32x4*)(p + 4);
    }
    f16x8 hi = cvt8(a, b);
    f16x8 lo = res8(a, b, hi);
    *(f16x8*)&XsH[r][c * 8] = hi;
    *(f16x8*)&XsL[r][c * 8] = lo;
  }
  __syncthreads();

  // ---- input GEMM: xf = x @ W_in.T + b_in (2-term: x hi/lo @ W f16) ----
  // Rows: lane lo16&7 -> rows 8..15 duplicate rows 0..7 (garbage D rows, OK).
  // 25 uniform stages. W from global f16 (depth-4 ring); x from LDS, frags
  // pre-split -> no per-stage VALU conversion.
  f32x4 acc  = {0.f, 0.f, 0.f, 0.f};
  f32x4 acc2 = {0.f, 0.f, 0.f, 0.f};
  const _Float16* xh = &XsH[lo16 & 7][0];
  const _Float16* xl = &XsL[lo16 & 7][0];
#pragma unroll 5
  for (int s = 0; s < 25; ++s) {
    const int k = s * 32 + quad * 8;
    f16x8 ahi = *(const f16x8*)(xh + k);
    f16x8 alo = *(const f16x8*)(xl + k);
    f16x8 bh  = WB[s & 3];
    if (s + 4 < 25) WB[s & 3] = *(const f16x8*)(wr + k + 4 * 32);
    acc  = MFMA(ahi, bh, acc);
    acc2 = MFMA(alo, bh, acc2);   // two independent chains
  }
  f32x4 xf;   // fixed-point input, f32, D-layout
#pragma unroll
  for (int i = 0; i < 4; ++i) xf[i] = acc[i] + acc2[i] + bi;

  // unconditional A-frag read: rows 8..15 duplicate rows 0..7 (garbage-OK)
#define ZREAD(pbuf, off) (*(const f16x8*)&Zb[pbuf][lo16 & 7][(off) + quad * 8])

  // Split writes: quads 2,3 hold bit-exact dups of quads 0,1's D rows, so
  // each quad writes 2 rows (0,1 / 4,5 / 2,3 / 6,7) -> tanh chain 4 -> 2.
#define ZWTANH(buf, e0, e1, e2, e3)                                       \
  { const float v0_ = (quad & 2) ? (e2) : (e0);                           \
    const float v1_ = (quad & 2) ? (e3) : (e1);                           \
    const int  rr_ = (quad & 1) * 4 + ((quad & 2) ? 2 : 0);               \
    Zb[buf][rr_][u0 + lo16]     = (_Float16)tanh_fast(v0_);               \
    Zb[buf][rr_ + 1][u0 + lo16] = (_Float16)tanh_fast(v1_); }
#define ZWRAW(buf, e0, e1, e2, e3)                                        \
  { const float v0_ = (quad & 2) ? (e2) : (e0);                           \
    const float v1_ = (quad & 2) ? (e3) : (e1);                           \
    const int  rr_ = (quad & 1) * 4 + ((quad & 2) ? 2 : 0);               \
    Zb[buf][rr_][u0 + lo16]     = (_Float16)(v0_);                        \
    Zb[buf][rr_ + 1][u0 + lo16] = (_Float16)(v1_); }

  // ---- z0 for wb=0 into buf 0 ----
  ZWTANH(0, xf[0], xf[1], xf[2], xf[3]);
  __syncthreads();

  // ---- 4 implicit blocks: z = tanh(z @ W.T + xf), Picard ----
#pragma unroll
  for (int wb = 0; wb < 4; ++wb) {
    f16x8 wn[4];
    if (wb < 3) {   // prefetch next W (f16 direct) during this block's rounds
      const _Float16* a = wsh + OFF_WB + (wb + 1) * UNITS * UNITS
                        + (size_t)(u0 + lo16) * UNITS;
#pragma unroll
      for (int s = 0; s < 4; ++s)
        wn[s] = *(const f16x8*)(a + s * 32 + quad * 8);
    }

#pragma unroll
    for (int it = 0; it < NIT - 1; ++it) {        // 3 in-loop rounds
      const int p = it & 1;
      f16x8 a0 = ZREAD(p, 0);
      f16x8 a1 = ZREAD(p, 32);
      f16x8 a2 = ZREAD(p, 64);
      f16x8 a3 = ZREAD(p, 96);
      f32x4 chi = xf;                         // chain 1: xf + A0W0 + A1W1
      f32x4 clo = {0.f, 0.f, 0.f, 0.f};       // chain 2: A2W2 + A3W3
      chi = MFMA(a0, wf[0], chi);
      clo = MFMA(a2, wf[2], clo);
      chi = MFMA(a1, wf[1], chi);
      clo = MFMA(a3, wf[3], clo);
      const int q = p ^ 1;
      ZWTANH(q, chi[0] + clo[0], chi[1] + clo[1],
                chi[2] + clo[2], chi[3] + clo[3]);
      __syncthreads();
    }
    // final iteration (reads buf (NIT-1)&1 = 1): output tanh stays f32 -> xf.
    // wb<3: write next z0 = tanh(xf') to buf 0 (last readers passed the
    // it=NIT-2 barrier -> race-free); wb==3: write z4 itself (head reads buf 0).
    {
      f16x8 a0 = ZREAD(1, 0);
      f16x8 a1 = ZREAD(1, 32);
      f16x8 a2 = ZREAD(1, 64);
      f16x8 a3 = ZREAD(1, 96);
      f32x4 chi = xf;
      f32x4 clo = {0.f, 0.f, 0.f, 0.f};
      chi = MFMA(a0, wf[0], chi);
      clo = MFMA(a2, wf[2], clo);
      chi = MFMA(a1, wf[1], chi);
      clo = MFMA(a3, wf[3], clo);
#pragma unroll
      for (int i = 0; i < 4; ++i) xf[i] = tanh_fast(chi[i] + clo[i]);
      if (wb < 3) {
        ZWTANH(0, xf[0], xf[1], xf[2], xf[3]);
      } else {
        ZWRAW(0, xf[0], xf[1], xf[2], xf[3]);
      }
      __syncthreads();
    }
    if (wb < 3) {
#pragma unroll
      for (int s = 0; s < 4; ++s) wf[s] = wn[s];
    }
  }

  // ---- head (wave 0 only): logits via MFMA with prefetched frags, softmax ----
  if (wave == 0) {
    f16x8 a0 = ZREAD(0, 0);
    f16x8 a1 = ZREAD(0, 32);
    f16x8 a2 = ZREAD(0, 64);
    f16x8 a3 = ZREAD(0, 96);
    f32x4 c = {0.f, 0.f, 0.f, 0.f};
    c = MFMA(a0, bf0, c);
    c = MFMA(a1, bf1, c);
    c = MFMA(a2, bf2, c);
    c = MFMA(a3, bf3, c);
    // D[m=quad*4+i][n=lo16]: rows 0..7 real (quads 0,1), classes lo16<10
    float pr[4];
#pragma unroll
    for (int i = 0; i < 4; ++i) {
      float v = (lo16 < D_OUT) ? (c[i] + bo) : -1e30f;
      float m = v;
#pragma unroll
      for (int d = 1; d < 16; d <<= 1) m = fmaxf(m, __shfl_xor(m, d, 16));
      float e = (lo16 < D_OUT) ? __expf(v - m) : 0.f;
      float sm = e;
#pragma unroll
      for (int d = 1; d < 16; d <<= 1) sm += __shfl_xor(sm, d, 16);
      pr[i] = e * rcp_fast(sm);
    }
    if (quad < 2 && lo16 < D_OUT) {
#pragma unroll
      for (int i = 0; i < 4; ++i)
        out[(size_t)(r0 + quad * 4 + i) * D_OUT + lo16] = pr[i];
    }
  }
}

extern "C" void kernel_launch(void* const* d_in, const int* in_sizes, int n_in,
                              void* d_out, int out_size, void* d_ws, size_t ws_size,
                              hipStream_t stream) {
  const float* x     = (const float*)d_in[0];
  const float* W_in  = (const float*)d_in[1];
  const float* b_in  = (const float*)d_in[2];
  const float* W1    = (const float*)d_in[3];
  const float* W2    = (const float*)d_in[4];
  const float* W3    = (const float*)d_in[5];
  const float* W4    = (const float*)d_in[6];
  const float* W_out = (const float*)d_in[7];
  const float* b_out = (const float*)d_in[8];
  float* outp = (float*)d_out;
  _Float16* wsh = (_Float16*)d_ws;

  // ws is re-poisoned by the harness each iteration -> prep must run each
  // replay (it is enqueued on the same stream, so it does).
  hipLaunchKernelGGL(prep_weights, dim3((WS_ELEMS + 511) / 512), dim3(512), 0,
                     stream, W_in, W1, W2, W3, W4, W_out, wsh);

  dim3 grid(B_ROWS / RPB);      // 256 blocks x 8 waves, full chip
  dim3 block(THREADS);
  hipLaunchKernelGGL(fused_net, grid, block, 0, stream,
                     x, b_in, b_out, wsh, outp);
}

// Round 3
// 83.448 us; speedup vs baseline: 2.8208x; 2.8208x over previous
//
#include <hip/hip_runtime.h>

// NewtonImplicitNet via Picard iteration, MFMA, 16-round edition.
// R19: fix R18's rule-#20 violation. R18 changed the input GEMM loop from
// "#pragma unroll 4 / s<24 + epilogue" to "#pragma unroll 5 / s<25", making
// WB[s&3] runtime-indexed -> compiler demoted the f16x8 ring to SCRATCH
// (VGPR dropped to 72, fused_net 170us, 7x regression). Fix: fully unroll
// the 25-stage loop -> s compile-time -> WB back in registers.
// R18's kept improvements (both bit-identical):
//  (1) x hi/lo f16 split done once in the LDS staging pass; GEMM reads
//      pre-split f16x8 fragments (no per-stage cvt8/res8 VALU).
//  (2) Picard-round writes split across dup quads (tanh chain 4 -> 2).
// Predicted: fused_net ~20us, headline ~84-86us, absmax 0.005859375 exact.

#define B_ROWS  2048
#define D_IN    784
#define UNITS   128
#define D_OUT   10
#define RPB     8       // rows per block -> 256 blocks, rows 0..7 real in M=16
#define THREADS 512
#define NIT     4       // even (buffer parity: final read = buf 1, z0 -> buf 0)
#define ZSTR    138     // f16 Z row stride: 69 dwords = 5 mod 32 (2-way max)
#define XF16S   808     // f16 x row stride: 404 dwords = 20 mod 32 (spread)
#define KPAD    800     // zero-padded K for input GEMM: 25 stages x 32

// f16 workspace layout (element offsets)
#define OFF_WIN  0                              // 128 x KPAD
#define OFF_WB   (UNITS * KPAD)                 // 102400: then 4 x 128 x 128
#define OFF_WOUT (OFF_WB + 4 * UNITS * UNITS)   // 167936: 10 x 128
#define WS_ELEMS (OFF_WOUT + D_OUT * UNITS)     // 169216 f16 = 338 KB << ws

typedef _Float16 f16x8 __attribute__((ext_vector_type(8)));
typedef float    f32x4 __attribute__((ext_vector_type(4)));

__device__ __forceinline__ float rcp_fast(float x) { return __builtin_amdgcn_rcpf(x); }

__device__ __forceinline__ float tanh_fast(float x) {
  float e = __expf(2.0f * x);
  return 1.0f - 2.0f * rcp_fast(e + 1.0f);
}

__device__ __forceinline__ f16x8 cvt8(f32x4 a, f32x4 b) {
  f16x8 r;
  r[0] = (_Float16)a[0]; r[1] = (_Float16)a[1]; r[2] = (_Float16)a[2]; r[3] = (_Float16)a[3];
  r[4] = (_Float16)b[0]; r[5] = (_Float16)b[1]; r[6] = (_Float16)b[2]; r[7] = (_Float16)b[3];
  return r;
}
__device__ __forceinline__ f16x8 res8(f32x4 a, f32x4 b, f16x8 hi) {
  f16x8 r;
  r[0] = (_Float16)(a[0] - (float)hi[0]); r[1] = (_Float16)(a[1] - (float)hi[1]);
  r[2] = (_Float16)(a[2] - (float)hi[2]); r[3] = (_Float16)(a[3] - (float)hi[3]);
  r[4] = (_Float16)(b[0] - (float)hi[4]); r[5] = (_Float16)(b[1] - (float)hi[5]);
  r[6] = (_Float16)(b[2] - (float)hi[6]); r[7] = (_Float16)(b[3] - (float)hi[7]);
  return r;
}

#define MFMA(a, b, c) __builtin_amdgcn_mfma_f32_16x16x32_f16((a), (b), (c), 0, 0, 0)

// Fragment conventions (validated R4-R15):
//   A: lane holds A[m=lo16][k = 32s + quad*8 + j], j=0..7
//   B: lane holds B[k = 32s + quad*8 + j][n=lo16]  (= Wrow[n][k..] row-major)
//   C/D: lane holds D[m = quad*4 + i][n=lo16], i=0..3
// D rows depend only on A rows -> A rows 8..15 dup rows 0..7 BIT-EXACTLY
// (same A content, same B) -> quads 2,3 hold duplicate D rows, exploited
// by the split writes below.

// ---- prep: round all weights to f16 once (bit-identical to in-kernel cvt8) ----
__global__ void prep_weights(const float* __restrict__ W_in,
                             const float* __restrict__ W1,
                             const float* __restrict__ W2,
                             const float* __restrict__ W3,
                             const float* __restrict__ W4,
                             const float* __restrict__ W_out,
                             _Float16* __restrict__ wsh)
{
  const int i = blockIdx.x * blockDim.x + threadIdx.x;
  if (i < OFF_WB) {                       // W_in, zero-padded K 784 -> 800
    const int u = i / KPAD;
    const int k = i - u * KPAD;
    wsh[i] = (k < D_IN) ? (_Float16)W_in[u * D_IN + k] : (_Float16)0.f;
  } else if (i < OFF_WOUT) {              // W1..W4 row-major 128x128
    const int j = i - OFF_WB;
    const int w = j >> 14;
    const int rc = j & 16383;
    const float* Wp = (w == 0) ? W1 : (w == 1) ? W2 : (w == 2) ? W3 : W4;
    wsh[i] = (_Float16)Wp[rc];
  } else if (i < WS_ELEMS) {              // W_out 10x128
    wsh[i] = (_Float16)W_out[i - OFF_WOUT];
  }
}

__global__ __launch_bounds__(THREADS, 1) void fused_net(
    const float* __restrict__ x,
    const float* __restrict__ b_in,
    const float* __restrict__ b_out,
    const _Float16* __restrict__ wsh,
    float* __restrict__ out)
{
  __shared__ __align__(16) _Float16 Zb[2][RPB][ZSTR];   // ~4.4 KB
  __shared__ __align__(16) _Float16 XsH[RPB][XF16S];    // ~12.9 KB x-hi
  __shared__ __align__(16) _Float16 XsL[RPB][XF16S];    // ~12.9 KB x-lo

  const int t    = threadIdx.x;
  const int wave = t >> 6;        // 0..7, N-tile: units [16w, 16w+16)
  const int l    = t & 63;
  const int lo16 = l & 15;
  const int quad = l >> 4;
  const int u0   = wave * 16;
  const int r0   = blockIdx.x * RPB;

  const float bi = b_in[u0 + lo16];   // early scalar load

  // ---- W1 fragments for wb=0: straight f16 loads (issued early, pending) ----
  f16x8 wf[4];
  {
    const _Float16* a = wsh + OFF_WB + (size_t)(u0 + lo16) * UNITS;
#pragma unroll
    for (int s = 0; s < 4; ++s)
      wf[s] = *(const f16x8*)(a + s * 32 + quad * 8);
  }

  // ---- head fragments hoisted: wave 0 loads W_out/b_out NOW (regs) ----
  f16x8 bf0 = {}, bf1 = {}, bf2 = {}, bf3 = {};
  float bo = 0.f;
  if (wave == 0) {
    const int cls = (lo16 < D_OUT) ? lo16 : 0;
    const _Float16* wo = wsh + OFF_WOUT + (size_t)cls * UNITS;
    if (lo16 < D_OUT) {
      bf0 = *(const f16x8*)(wo + 0 * 32 + quad * 8);
      bf1 = *(const f16x8*)(wo + 1 * 32 + quad * 8);
      bf2 = *(const f16x8*)(wo + 2 * 32 + quad * 8);
      bf3 = *(const f16x8*)(wo + 3 * 32 + quad * 8);
      bo  = b_out[cls];
    }
  }

  // ---- W_in fragment ring: first 4 stages issued before x staging ----
  const _Float16* wr = wsh + OFF_WIN + (size_t)(u0 + lo16) * KPAD;
  f16x8 WB[4];
#pragma unroll
  for (int j = 0; j < 4; ++j)
    WB[j] = *(const f16x8*)(wr + j * 32 + quad * 8);

  // ---- stage x rows into LDS as f16 hi/lo (one-touch split; zero-padded) ----
  for (int i = t; i < RPB * (KPAD / 8); i += THREADS) {   // 800 8-elem slots
    const int r = i / (KPAD / 8);
    const int c = i - r * (KPAD / 8);
    f32x4 a = {0.f, 0.f, 0.f, 0.f}, b = {0.f, 0.f, 0.f, 0.f};
    if (c < D_IN / 8) {   // c*8+8 <= 784 for c < 98; 98,99 stay zero
      const float* p = x + (size_t)(r0 + r) * D_IN + c * 8;
      a = *(const f32x4*)p;
      b = *(const f32x4*)(p + 4);
    }
    f16x8 hi = cvt8(a, b);
    f16x8 lo = res8(a, b, hi);
    *(f16x8*)&XsH[r][c * 8] = hi;
    *(f16x8*)&XsL[r][c * 8] = lo;
  }
  __syncthreads();

  // ---- input GEMM: xf = x @ W_in.T + b_in (2-term: x hi/lo @ W f16) ----
  // Rows: lane lo16&7 -> rows 8..15 duplicate rows 0..7 (garbage D rows, OK).
  // 25 uniform stages, FULLY unrolled (s compile-time so WB[s&3] is static
  // register indexing -- rule #20: partial unroll put WB in scratch, 7x).
  f32x4 acc  = {0.f, 0.f, 0.f, 0.f};
  f32x4 acc2 = {0.f, 0.f, 0.f, 0.f};
  const _Float16* xh = &XsH[lo16 & 7][0];
  const _Float16* xl = &XsL[lo16 & 7][0];
#pragma unroll
  for (int s = 0; s < 25; ++s) {
    const int k = s * 32 + quad * 8;
    f16x8 ahi = *(const f16x8*)(xh + k);
    f16x8 alo = *(const f16x8*)(xl + k);
    f16x8 bh  = WB[s & 3];
    if (s + 4 < 25) WB[s & 3] = *(const f16x8*)(wr + k + 4 * 32);
    acc  = MFMA(ahi, bh, acc);
    acc2 = MFMA(alo, bh, acc2);   // two independent chains
  }
  f32x4 xf;   // fixed-point input, f32, D-layout
#pragma unroll
  for (int i = 0; i < 4; ++i) xf[i] = acc[i] + acc2[i] + bi;

  // unconditional A-frag read: rows 8..15 duplicate rows 0..7 (garbage-OK)
#define ZREAD(pbuf, off) (*(const f16x8*)&Zb[pbuf][lo16 & 7][(off) + quad * 8])

  // Split writes: quads 2,3 hold bit-exact dups of quads 0,1's D rows, so
  // each quad writes 2 rows (0,1 / 4,5 / 2,3 / 6,7) -> tanh chain 4 -> 2.
#define ZWTANH(buf, e0, e1, e2, e3)                                       \
  { const float v0_ = (quad & 2) ? (e2) : (e0);                           \
    const float v1_ = (quad & 2) ? (e3) : (e1);                           \
    const int  rr_ = (quad & 1) * 4 + ((quad & 2) ? 2 : 0);               \
    Zb[buf][rr_][u0 + lo16]     = (_Float16)tanh_fast(v0_);               \
    Zb[buf][rr_ + 1][u0 + lo16] = (_Float16)tanh_fast(v1_); }
#define ZWRAW(buf, e0, e1, e2, e3)                                        \
  { const float v0_ = (quad & 2) ? (e2) : (e0);                           \
    const float v1_ = (quad & 2) ? (e3) : (e1);                           \
    const int  rr_ = (quad & 1) * 4 + ((quad & 2) ? 2 : 0);               \
    Zb[buf][rr_][u0 + lo16]     = (_Float16)(v0_);                        \
    Zb[buf][rr_ + 1][u0 + lo16] = (_Float16)(v1_); }

  // ---- z0 for wb=0 into buf 0 ----
  ZWTANH(0, xf[0], xf[1], xf[2], xf[3]);
  __syncthreads();

  // ---- 4 implicit blocks: z = tanh(z @ W.T + xf), Picard ----
#pragma unroll
  for (int wb = 0; wb < 4; ++wb) {
    f16x8 wn[4];
    if (wb < 3) {   // prefetch next W (f16 direct) during this block's rounds
      const _Float16* a = wsh + OFF_WB + (wb + 1) * UNITS * UNITS
                        + (size_t)(u0 + lo16) * UNITS;
#pragma unroll
      for (int s = 0; s < 4; ++s)
        wn[s] = *(const f16x8*)(a + s * 32 + quad * 8);
    }

#pragma unroll
    for (int it = 0; it < NIT - 1; ++it) {        // 3 in-loop rounds
      const int p = it & 1;
      f16x8 a0 = ZREAD(p, 0);
      f16x8 a1 = ZREAD(p, 32);
      f16x8 a2 = ZREAD(p, 64);
      f16x8 a3 = ZREAD(p, 96);
      f32x4 chi = xf;                         // chain 1: xf + A0W0 + A1W1
      f32x4 clo = {0.f, 0.f, 0.f, 0.f};       // chain 2: A2W2 + A3W3
      chi = MFMA(a0, wf[0], chi);
      clo = MFMA(a2, wf[2], clo);
      chi = MFMA(a1, wf[1], chi);
      clo = MFMA(a3, wf[3], clo);
      const int q = p ^ 1;
      ZWTANH(q, chi[0] + clo[0], chi[1] + clo[1],
                chi[2] + clo[2], chi[3] + clo[3]);
      __syncthreads();
    }
    // final iteration (reads buf (NIT-1)&1 = 1): output tanh stays f32 -> xf.
    // wb<3: write next z0 = tanh(xf') to buf 0 (last readers passed the
    // it=NIT-2 barrier -> race-free); wb==3: write z4 itself (head reads buf 0).
    {
      f16x8 a0 = ZREAD(1, 0);
      f16x8 a1 = ZREAD(1, 32);
      f16x8 a2 = ZREAD(1, 64);
      f16x8 a3 = ZREAD(1, 96);
      f32x4 chi = xf;
      f32x4 clo = {0.f, 0.f, 0.f, 0.f};
      chi = MFMA(a0, wf[0], chi);
      clo = MFMA(a2, wf[2], clo);
      chi = MFMA(a1, wf[1], chi);
      clo = MFMA(a3, wf[3], clo);
#pragma unroll
      for (int i = 0; i < 4; ++i) xf[i] = tanh_fast(chi[i] + clo[i]);
      if (wb < 3) {
        ZWTANH(0, xf[0], xf[1], xf[2], xf[3]);
      } else {
        ZWRAW(0, xf[0], xf[1], xf[2], xf[3]);
      }
      __syncthreads();
    }
    if (wb < 3) {
#pragma unroll
      for (int s = 0; s < 4; ++s) wf[s] = wn[s];
    }
  }

  // ---- head (wave 0 only): logits via MFMA with prefetched frags, softmax ----
  if (wave == 0) {
    f16x8 a0 = ZREAD(0, 0);
    f16x8 a1 = ZREAD(0, 32);
    f16x8 a2 = ZREAD(0, 64);
    f16x8 a3 = ZREAD(0, 96);
    f32x4 c = {0.f, 0.f, 0.f, 0.f};
    c = MFMA(a0, bf0, c);
    c = MFMA(a1, bf1, c);
    c = MFMA(a2, bf2, c);
    c = MFMA(a3, bf3, c);
    // D[m=quad*4+i][n=lo16]: rows 0..7 real (quads 0,1), classes lo16<10
    float pr[4];
#pragma unroll
    for (int i = 0; i < 4; ++i) {
      float v = (lo16 < D_OUT) ? (c[i] + bo) : -1e30f;
      float m = v;
#pragma unroll
      for (int d = 1; d < 16; d <<= 1) m = fmaxf(m, __shfl_xor(m, d, 16));
      float e = (lo16 < D_OUT) ? __expf(v - m) : 0.f;
      float sm = e;
#pragma unroll
      for (int d = 1; d < 16; d <<= 1) sm += __shfl_xor(sm, d, 16);
      pr[i] = e * rcp_fast(sm);
    }
    if (quad < 2 && lo16 < D_OUT) {
#pragma unroll
      for (int i = 0; i < 4; ++i)
        out[(size_t)(r0 + quad * 4 + i) * D_OUT + lo16] = pr[i];
    }
  }
}

extern "C" void kernel_launch(void* const* d_in, const int* in_sizes, int n_in,
                              void* d_out, int out_size, void* d_ws, size_t ws_size,
                              hipStream_t stream) {
  const float* x     = (const float*)d_in[0];
  const float* W_in  = (const float*)d_in[1];
  const float* b_in  = (const float*)d_in[2];
  const float* W1    = (const float*)d_in[3];
  const float* W2    = (const float*)d_in[4];
  const float* W3    = (const float*)d_in[5];
  const float* W4    = (const float*)d_in[6];
  const float* W_out = (const float*)d_in[7];
  const float* b_out = (const float*)d_in[8];
  float* outp = (float*)d_out;
  _Float16* wsh = (_Float16*)d_ws;

  // ws is re-poisoned by the harness each iteration -> prep must run each
  // replay (it is enqueued on the same stream, so it does).
  hipLaunchKernelGGL(prep_weights, dim3((WS_ELEMS + 511) / 512), dim3(512), 0,
                     stream, W_in, W1, W2, W3, W4, W_out, wsh);

  dim3 grid(B_ROWS / RPB);      // 256 blocks x 8 waves, full chip
  dim3 block(THREADS);
  hipLaunchKernelGGL(fused_net, grid, block, 0, stream,
                     x, b_in, b_out, wsh, outp);
}

// Round 4
// 83.236 us; speedup vs baseline: 2.8279x; 1.0025x over previous
//
#include <hip/hip_runtime.h>

// NewtonImplicitNet via Picard iteration, MFMA, 16-round edition.
// R20: input-GEMM hi/lo-in-rows. A rows 8..15 were dup of 0..7 (wasted MFMA
// capacity). Now lanes lo16 0..7 carry x_hi rows 0..7, lanes 8..15 carry
// x_lo rows 0..7 -> ONE MFMA + ONE LDS read per stage (was 2+2); D rows
// 0..7 = hi partial, 8..15 = lo partial; recombined by __shfl_xor(.,32)
// + add (quad q <-> q^2 pairs D[r] with D[r+8]). Bit-identical: per-row
// chains carry the same values in the same order; (hi+lo)+bi vs (lo+hi)+bi
// is IEEE-commutative-equal. Also W_in ring 4 -> 8 deep (covers L2/L3
// latency; indices static under full unroll -- rule #20 guarded).
// Predicted: -0.5..2.5us, absmax exactly 0.005859375. Neutral -> latency
// floor, declare practical roofline.

#define B_ROWS  2048
#define D_IN    784
#define UNITS   128
#define D_OUT   10
#define RPB     8       // rows per block -> 256 blocks, rows 0..7 real in M=16
#define THREADS 512
#define NIT     4       // even (buffer parity: final read = buf 1, z0 -> buf 0)
#define ZSTR    138     // f16 Z row stride: 69 dwords = 5 mod 32 (2-way max)
#define XF16S   808     // f16 x row stride: 404 dwords = 20 mod 32 (spread)
#define KPAD    800     // zero-padded K for input GEMM: 25 stages x 32

// f16 workspace layout (element offsets)
#define OFF_WIN  0                              // 128 x KPAD
#define OFF_WB   (UNITS * KPAD)                 // 102400: then 4 x 128 x 128
#define OFF_WOUT (OFF_WB + 4 * UNITS * UNITS)   // 167936: 10 x 128
#define WS_ELEMS (OFF_WOUT + D_OUT * UNITS)     // 169216 f16 = 338 KB << ws

typedef _Float16 f16x8 __attribute__((ext_vector_type(8)));
typedef float    f32x4 __attribute__((ext_vector_type(4)));

__device__ __forceinline__ float rcp_fast(float x) { return __builtin_amdgcn_rcpf(x); }

__device__ __forceinline__ float tanh_fast(float x) {
  float e = __expf(2.0f * x);
  return 1.0f - 2.0f * rcp_fast(e + 1.0f);
}

__device__ __forceinline__ f16x8 cvt8(f32x4 a, f32x4 b) {
  f16x8 r;
  r[0] = (_Float16)a[0]; r[1] = (_Float16)a[1]; r[2] = (_Float16)a[2]; r[3] = (_Float16)a[3];
  r[4] = (_Float16)b[0]; r[5] = (_Float16)b[1]; r[6] = (_Float16)b[2]; r[7] = (_Float16)b[3];
  return r;
}
__device__ __forceinline__ f16x8 res8(f32x4 a, f32x4 b, f16x8 hi) {
  f16x8 r;
  r[0] = (_Float16)(a[0] - (float)hi[0]); r[1] = (_Float16)(a[1] - (float)hi[1]);
  r[2] = (_Float16)(a[2] - (float)hi[2]); r[3] = (_Float16)(a[3] - (float)hi[3]);
  r[4] = (_Float16)(b[0] - (float)hi[4]); r[5] = (_Float16)(b[1] - (float)hi[5]);
  r[6] = (_Float16)(b[2] - (float)hi[6]); r[7] = (_Float16)(b[7] - (float)hi[7]);
  return r;
}

#define MFMA(a, b, c) __builtin_amdgcn_mfma_f32_16x16x32_f16((a), (b), (c), 0, 0, 0)

// Fragment conventions (validated R4-R15):
//   A: lane holds A[m=lo16][k = 32s + quad*8 + j], j=0..7
//   B: lane holds B[k = 32s + quad*8 + j][n=lo16]  (= Wrow[n][k..] row-major)
//   C/D: lane holds D[m = quad*4 + i][n=lo16], i=0..3
// Input GEMM: A rows 0..7 = x_hi rows 0..7, rows 8..15 = x_lo rows 0..7.
// Picard rounds: A rows 8..15 dup rows 0..7 BIT-EXACTLY -> quads 2,3 hold
// duplicate D rows, exploited by the split writes below.

// ---- prep: round all weights to f16 once (bit-identical to in-kernel cvt8) ----
__global__ void prep_weights(const float* __restrict__ W_in,
                             const float* __restrict__ W1,
                             const float* __restrict__ W2,
                             const float* __restrict__ W3,
                             const float* __restrict__ W4,
                             const float* __restrict__ W_out,
                             _Float16* __restrict__ wsh)
{
  const int i = blockIdx.x * blockDim.x + threadIdx.x;
  if (i < OFF_WB) {                       // W_in, zero-padded K 784 -> 800
    const int u = i / KPAD;
    const int k = i - u * KPAD;
    wsh[i] = (k < D_IN) ? (_Float16)W_in[u * D_IN + k] : (_Float16)0.f;
  } else if (i < OFF_WOUT) {              // W1..W4 row-major 128x128
    const int j = i - OFF_WB;
    const int w = j >> 14;
    const int rc = j & 16383;
    const float* Wp = (w == 0) ? W1 : (w == 1) ? W2 : (w == 2) ? W3 : W4;
    wsh[i] = (_Float16)Wp[rc];
  } else if (i < WS_ELEMS) {              // W_out 10x128
    wsh[i] = (_Float16)W_out[i - OFF_WOUT];
  }
}

__global__ __launch_bounds__(THREADS, 1) void fused_net(
    const float* __restrict__ x,
    const float* __restrict__ b_in,
    const float* __restrict__ b_out,
    const _Float16* __restrict__ wsh,
    float* __restrict__ out)
{
  __shared__ __align__(16) _Float16 Zb[2][RPB][ZSTR];   // ~4.4 KB
  __shared__ __align__(16) _Float16 XsH[RPB][XF16S];    // ~12.9 KB x-hi
  __shared__ __align__(16) _Float16 XsL[RPB][XF16S];    // ~12.9 KB x-lo

  const int t    = threadIdx.x;
  const int wave = t >> 6;        // 0..7, N-tile: units [16w, 16w+16)
  const int l    = t & 63;
  const int lo16 = l & 15;
  const int quad = l >> 4;
  const int u0   = wave * 16;
  const int r0   = blockIdx.x * RPB;

  const float bi = b_in[u0 + lo16];   // early scalar load

  // ---- W1 fragments for wb=0: straight f16 loads (issued early, pending) ----
  f16x8 wf[4];
  {
    const _Float16* a = wsh + OFF_WB + (size_t)(u0 + lo16) * UNITS;
#pragma unroll
    for (int s = 0; s < 4; ++s)
      wf[s] = *(const f16x8*)(a + s * 32 + quad * 8);
  }

  // ---- head fragments hoisted: wave 0 loads W_out/b_out NOW (regs) ----
  f16x8 bf0 = {}, bf1 = {}, bf2 = {}, bf3 = {};
  float bo = 0.f;
  if (wave == 0) {
    const int cls = (lo16 < D_OUT) ? lo16 : 0;
    const _Float16* wo = wsh + OFF_WOUT + (size_t)cls * UNITS;
    if (lo16 < D_OUT) {
      bf0 = *(const f16x8*)(wo + 0 * 32 + quad * 8);
      bf1 = *(const f16x8*)(wo + 1 * 32 + quad * 8);
      bf2 = *(const f16x8*)(wo + 2 * 32 + quad * 8);
      bf3 = *(const f16x8*)(wo + 3 * 32 + quad * 8);
      bo  = b_out[cls];
    }
  }

  // ---- W_in fragment ring: first 8 stages issued before x staging ----
  const _Float16* wr = wsh + OFF_WIN + (size_t)(u0 + lo16) * KPAD;
  f16x8 WB[8];
#pragma unroll
  for (int j = 0; j < 8; ++j)
    WB[j] = *(const f16x8*)(wr + j * 32 + quad * 8);

  // ---- stage x rows into LDS as f16 hi/lo (one-touch split; zero-padded) ----
  for (int i = t; i < RPB * (KPAD / 8); i += THREADS) {   // 800 8-elem slots
    const int r = i / (KPAD / 8);
    const int c = i - r * (KPAD / 8);
    f32x4 a = {0.f, 0.f, 0.f, 0.f}, b = {0.f, 0.f, 0.f, 0.f};
    if (c < D_IN / 8) {   // c*8+8 <= 784 for c < 98; 98,99 stay zero
      const float* p = x + (size_t)(r0 + r) * D_IN + c * 8;
      a = *(const f32x4*)p;
      b = *(const f32x4*)(p + 4);
    }
    f16x8 hi = cvt8(a, b);
    f16x8 lo;   // residual (same math as res8, inline to avoid typo risk)
#pragma unroll
    for (int j = 0; j < 4; ++j) {
      lo[j]     = (_Float16)(a[j] - (float)hi[j]);
      lo[j + 4] = (_Float16)(b[j] - (float)hi[j + 4]);
    }
    *(f16x8*)&XsH[r][c * 8] = hi;
    *(f16x8*)&XsL[r][c * 8] = lo;
  }
  __syncthreads();

  // ---- input GEMM: xf = x @ W_in.T + b_in, hi/lo-in-rows (1 MFMA/stage) ----
  // A rows 0..7 (lanes lo16<8) = x_hi rows; rows 8..15 (lanes lo16>=8) =
  // x_lo rows. D rows 0..7 = hi partial, 8..15 = lo partial, recombined by
  // shfl_xor(32): quad q <-> q^2 pairs D[r] with D[r+8]. Per-row chains are
  // bitwise identical to the old 2-chain version; (hi+lo) vs (lo+hi) is
  // IEEE-commutative-equal -> absmax must stay 0.005859375 exactly.
  f32x4 acc = {0.f, 0.f, 0.f, 0.f};
  const _Float16* xrow = (lo16 < 8) ? &XsH[lo16][0] : &XsL[lo16 & 7][0];
#pragma unroll
  for (int s = 0; s < 25; ++s) {
    const int k = s * 32 + quad * 8;
    f16x8 af = *(const f16x8*)(xrow + k);
    f16x8 bh = WB[s & 7];
    if (s + 8 < 25) WB[s & 7] = *(const f16x8*)(wr + k + 8 * 32);
    acc = MFMA(af, bh, acc);
  }
  f32x4 xf;   // fixed-point input, f32, D-layout (rows 0..7, quads 2,3 dup)
#pragma unroll
  for (int i = 0; i < 4; ++i) {
    const float other = __shfl_xor(acc[i], 32);
    xf[i] = (acc[i] + other) + bi;
  }

  // unconditional A-frag read: rows 8..15 duplicate rows 0..7 (garbage-OK)
#define ZREAD(pbuf, off) (*(const f16x8*)&Zb[pbuf][lo16 & 7][(off) + quad * 8])

  // Split writes: quads 2,3 hold bit-exact dups of quads 0,1's D rows, so
  // each quad writes 2 rows (0,1 / 4,5 / 2,3 / 6,7) -> tanh chain 4 -> 2.
#define ZWTANH(buf, e0, e1, e2, e3)                                       \
  { const float v0_ = (quad & 2) ? (e2) : (e0);                           \
    const float v1_ = (quad & 2) ? (e3) : (e1);                           \
    const int  rr_ = (quad & 1) * 4 + ((quad & 2) ? 2 : 0);               \
    Zb[buf][rr_][u0 + lo16]     = (_Float16)tanh_fast(v0_);               \
    Zb[buf][rr_ + 1][u0 + lo16] = (_Float16)tanh_fast(v1_); }
#define ZWRAW(buf, e0, e1, e2, e3)                                        \
  { const float v0_ = (quad & 2) ? (e2) : (e0);                           \
    const float v1_ = (quad & 2) ? (e3) : (e1);                           \
    const int  rr_ = (quad & 1) * 4 + ((quad & 2) ? 2 : 0);               \
    Zb[buf][rr_][u0 + lo16]     = (_Float16)(v0_);                        \
    Zb[buf][rr_ + 1][u0 + lo16] = (_Float16)(v1_); }

  // ---- z0 for wb=0 into buf 0 ----
  ZWTANH(0, xf[0], xf[1], xf[2], xf[3]);
  __syncthreads();

  // ---- 4 implicit blocks: z = tanh(z @ W.T + xf), Picard ----
#pragma unroll
  for (int wb = 0; wb < 4; ++wb) {
    f16x8 wn[4];
    if (wb < 3) {   // prefetch next W (f16 direct) during this block's rounds
      const _Float16* a = wsh + OFF_WB + (wb + 1) * UNITS * UNITS
                        + (size_t)(u0 + lo16) * UNITS;
#pragma unroll
      for (int s = 0; s < 4; ++s)
        wn[s] = *(const f16x8*)(a + s * 32 + quad * 8);
    }

#pragma unroll
    for (int it = 0; it < NIT - 1; ++it) {        // 3 in-loop rounds
      const int p = it & 1;
      f16x8 a0 = ZREAD(p, 0);
      f16x8 a1 = ZREAD(p, 32);
      f16x8 a2 = ZREAD(p, 64);
      f16x8 a3 = ZREAD(p, 96);
      f32x4 chi = xf;                         // chain 1: xf + A0W0 + A1W1
      f32x4 clo = {0.f, 0.f, 0.f, 0.f};       // chain 2: A2W2 + A3W3
      chi = MFMA(a0, wf[0], chi);
      clo = MFMA(a2, wf[2], clo);
      chi = MFMA(a1, wf[1], chi);
      clo = MFMA(a3, wf[3], clo);
      const int q = p ^ 1;
      ZWTANH(q, chi[0] + clo[0], chi[1] + clo[1],
                chi[2] + clo[2], chi[3] + clo[3]);
      __syncthreads();
    }
    // final iteration (reads buf (NIT-1)&1 = 1): output tanh stays f32 -> xf.
    // wb<3: write next z0 = tanh(xf') to buf 0 (last readers passed the
    // it=NIT-2 barrier -> race-free); wb==3: write z4 itself (head reads buf 0).
    {
      f16x8 a0 = ZREAD(1, 0);
      f16x8 a1 = ZREAD(1, 32);
      f16x8 a2 = ZREAD(1, 64);
      f16x8 a3 = ZREAD(1, 96);
      f32x4 chi = xf;
      f32x4 clo = {0.f, 0.f, 0.f, 0.f};
      chi = MFMA(a0, wf[0], chi);
      clo = MFMA(a2, wf[2], clo);
      chi = MFMA(a1, wf[1], chi);
      clo = MFMA(a3, wf[3], clo);
#pragma unroll
      for (int i = 0; i < 4; ++i) xf[i] = tanh_fast(chi[i] + clo[i]);
      if (wb < 3) {
        ZWTANH(0, xf[0], xf[1], xf[2], xf[3]);
      } else {
        ZWRAW(0, xf[0], xf[1], xf[2], xf[3]);
      }
      __syncthreads();
    }
    if (wb < 3) {
#pragma unroll
      for (int s = 0; s < 4; ++s) wf[s] = wn[s];
    }
  }

  // ---- head (wave 0 only): logits via MFMA with prefetched frags, softmax ----
  if (wave == 0) {
    f16x8 a0 = ZREAD(0, 0);
    f16x8 a1 = ZREAD(0, 32);
    f16x8 a2 = ZREAD(0, 64);
    f16x8 a3 = ZREAD(0, 96);
    f32x4 c = {0.f, 0.f, 0.f, 0.f};
    c = MFMA(a0, bf0, c);
    c = MFMA(a1, bf1, c);
    c = MFMA(a2, bf2, c);
    c = MFMA(a3, bf3, c);
    // D[m=quad*4+i][n=lo16]: rows 0..7 real (quads 0,1), classes lo16<10
    float pr[4];
#pragma unroll
    for (int i = 0; i < 4; ++i) {
      float v = (lo16 < D_OUT) ? (c[i] + bo) : -1e30f;
      float m = v;
#pragma unroll
      for (int d = 1; d < 16; d <<= 1) m = fmaxf(m, __shfl_xor(m, d, 16));
      float e = (lo16 < D_OUT) ? __expf(v - m) : 0.f;
      float sm = e;
#pragma unroll
      for (int d = 1; d < 16; d <<= 1) sm += __shfl_xor(sm, d, 16);
      pr[i] = e * rcp_fast(sm);
    }
    if (quad < 2 && lo16 < D_OUT) {
#pragma unroll
      for (int i = 0; i < 4; ++i)
        out[(size_t)(r0 + quad * 4 + i) * D_OUT + lo16] = pr[i];
    }
  }
}

extern "C" void kernel_launch(void* const* d_in, const int* in_sizes, int n_in,
                              void* d_out, int out_size, void* d_ws, size_t ws_size,
                              hipStream_t stream) {
  const float* x     = (const float*)d_in[0];
  const float* W_in  = (const float*)d_in[1];
  const float* b_in  = (const float*)d_in[2];
  const float* W1    = (const float*)d_in[3];
  const float* W2    = (const float*)d_in[4];
  const float* W3    = (const float*)d_in[5];
  const float* W4    = (const float*)d_in[6];
  const float* W_out = (const float*)d_in[7];
  const float* b_out = (const float*)d_in[8];
  float* outp = (float*)d_out;
  _Float16* wsh = (_Float16*)d_ws;

  // ws is re-poisoned by the harness each iteration -> prep must run each
  // replay (it is enqueued on the same stream, so it does).
  hipLaunchKernelGGL(prep_weights, dim3((WS_ELEMS + 511) / 512), dim3(512), 0,
                     stream, W_in, W1, W2, W3, W4, W_out, wsh);

  dim3 grid(B_ROWS / RPB);      // 256 blocks x 8 waves, full chip
  dim3 block(THREADS);
  hipLaunchKernelGGL(fused_net, grid, block, 0, stream,
                     x, b_in, b_out, wsh, outp);
}